// Round 11
// baseline (3949.982 us; speedup 1.0000x reference)
//
#include <hip/hip_runtime.h>
#include <cstdint>

typedef __bf16 bf16;
typedef __bf16 bf16x8 __attribute__((ext_vector_type(8)));
typedef float  f32x4  __attribute__((ext_vector_type(4)));

#define BARRIER()    asm volatile("s_barrier" ::: "memory")
#define WAIT_LGKM0() asm volatile("s_waitcnt lgkmcnt(0)" ::: "memory")
#define WAIT_VM(n)   asm volatile("s_waitcnt vmcnt(" #n ")" ::: "memory")

// ---------------------------------------------------------------------------
// Fused prep kernel: hf-GEMM (320 blocks) | hg-GEMM (90) | W2 transpose (640).
// ---------------------------------------------------------------------------
__device__ void gemm_small_body(
    const float* __restrict__ A, const float* __restrict__ Bm,
    const float* __restrict__ bias, bf16* __restrict__ Cout,
    int M, int N, int K, int bx, int by)
{
    __shared__ float As[64][20];
    __shared__ float Bs[16][68];
    const int tid = threadIdx.x;
    const int m0 = bx * 64, n0 = by * 64;
    const int tx = tid & 15, ty = tid >> 4;
    const int arow = tid >> 2, ak = (tid & 3) << 2;
    const int bk = tid >> 4, bc = (tid & 15) << 2;
    const bool avalid = (m0 + arow) < M;
    float acc[4][4] = {};

    for (int k0 = 0; k0 < K; k0 += 16) {
        float4 av = make_float4(0.f, 0.f, 0.f, 0.f);
        if (avalid) av = *(const float4*)&A[(size_t)(m0 + arow) * K + k0 + ak];
        float4 bv = *(const float4*)&Bm[(size_t)(k0 + bk) * N + n0 + bc];
        __syncthreads();
        *(float4*)&As[arow][ak] = av;
        *(float4*)&Bs[bk][bc] = bv;
        __syncthreads();
#pragma unroll
        for (int k = 0; k < 16; ++k) {
            float a[4], b[4];
#pragma unroll
            for (int i = 0; i < 4; ++i) a[i] = As[ty * 4 + i][k];
#pragma unroll
            for (int j = 0; j < 4; ++j) b[j] = Bs[k][tx * 4 + j];
#pragma unroll
            for (int i = 0; i < 4; ++i)
#pragma unroll
                for (int j = 0; j < 4; ++j) acc[i][j] += a[i] * b[j];
        }
    }
#pragma unroll
    for (int i = 0; i < 4; ++i) {
        int row = m0 + ty * 4 + i;
        if (row >= M) continue;
#pragma unroll
        for (int j = 0; j < 4; ++j) {
            int col = n0 + tx * 4 + j;
            float v = acc[i][j] + (bias ? bias[col] : 0.f);
            Cout[(size_t)row * N + col] = (bf16)v;
        }
    }
}

__device__ void w2t_body(const float* __restrict__ W2, bf16* __restrict__ W2T,
                         int bx, int by)
{
    __shared__ float t[32][33];
    const int tx = threadIdx.x & 31, ty = threadIdx.x >> 5;  // 32 x 8
    const int n0 = bx * 32, k0 = by * 32;
#pragma unroll
    for (int i = 0; i < 4; ++i)
        t[ty + i * 8][tx] = W2[(size_t)(k0 + ty + i * 8) * 1024 + n0 + tx];
    __syncthreads();
#pragma unroll
    for (int i = 0; i < 4; ++i)
        W2T[(size_t)(n0 + ty + i * 8) * 640 + k0 + tx] = (bf16)t[tx][ty + i * 8];
}

__global__ __launch_bounds__(256) void prep(
    const float* __restrict__ f, const float* __restrict__ g,
    const float* __restrict__ W1, const float* __restrict__ b1,
    const float* __restrict__ W2,
    bf16* __restrict__ hf, bf16* __restrict__ hgb, bf16* __restrict__ W2T)
{
    const int bid = blockIdx.x;
    if (bid < 320) {
        gemm_small_body(f, W1, nullptr, hf, 2048, 640, 1024, bid % 32, bid / 32);
    } else if (bid < 410) {
        int b = bid - 320;
        gemm_small_body(g, W1 + 1024 * 640, b1, hgb, 520, 640, 320, b % 9, b / 9);
    } else {
        int b = bid - 410;
        w2t_body(W2, W2T, b % 32, b / 32);
    }
}

// ---------------------------------------------------------------------------
// ABLATION PROBES of the R6 structure (BM=128 BN=128, 4 waves, 3 blocks/CU,
// 2 barriers/tile). 80 K-tile iterations (8 reps), half grid. Output garbage;
// overwritten by the final correct joint_main.
//   V=0 full | V=1 no A-LDS round-trip | V=2 no MFMA (reads sunk) |
//   V=3 no B-DMA | V=4 no barriers
// ---------------------------------------------------------------------------
template<int V>
__global__ __launch_bounds__(256, 3) void joint_probe(
    const bf16* __restrict__ hf, const bf16* __restrict__ hgb,
    const bf16* __restrict__ W2T, const float* __restrict__ b2,
    float* __restrict__ out)
{
    __shared__ bf16 As[128 * 64];
    __shared__ bf16 Bs[128 * 64];
    const int tid = threadIdx.x;
    const int n0 = blockIdx.x * 128;
    const int m0 = blockIdx.y * 128;

    const int r  = tid >> 1;
    const int kh = (tid & 1) << 5;
    const int c0 = (tid & 1) << 2;
    int aoff[4];
#pragma unroll
    for (int c = 0; c < 4; ++c)
        aoff[c] = r * 64 + (((c0 + c) ^ (r & 7)) << 3);

    const int m  = m0 + r;
    const int bt = m / 65;
    const int uu = m - bt * 65;
    const int bb = bt >> 8;
    const bf16* hfp = hf  + (size_t)bt * 640 + kh;
    const bf16* hgp = hgb + (size_t)(bb * 65 + uu) * 640 + kh;

    const int wid = tid >> 6, lane = tid & 63;
    const int wr = wid >> 1, wc = wid & 1;
    const int lg = lane >> 4, l15 = lane & 15;

    f32x4 acc[4][4] = {};
    bf16x8 F[4], G[4];
    bf16x8 Og[4];                    // V1 register A-path

    auto loadA = [&](int k0) {
#pragma unroll
        for (int i = 0; i < 4; ++i) {
            F[i] = *(const bf16x8*)(hfp + k0 + i * 8);
            G[i] = *(const bf16x8*)(hgp + k0 + i * 8);
        }
    };
    auto stageB = [&](int k0) {
        const char* w2b = (const char*)W2T + (size_t)k0 * 2;
#pragma unroll
        for (int call = 0; call < 4; ++call) {
            int chunk = call * 256 + tid;
            int brow = chunk >> 3, c = chunk & 7;
            const char* src = w2b + (size_t)(n0 + brow) * 1280
                                  + ((c ^ (brow & 7)) << 4);
            __builtin_amdgcn_global_load_lds(
                (const __attribute__((address_space(1))) uint32_t*)src,
                (__attribute__((address_space(3))) uint32_t*)&Bs[chunk << 3],
                16, 0, 0);
        }
    };
    auto genA = [&]() {
#pragma unroll
        for (int c = 0; c < 4; ++c) {
            bf16x8 O;
#pragma unroll
            for (int i = 0; i < 8; ++i) {
                float s = (float)F[c][i] + (float)G[c][i];
                O[i] = (bf16)fmaxf(s, 0.f);
            }
            if constexpr (V == 1) Og[c] = O;
            else *(bf16x8*)&As[aoff[c]] = O;
        }
    };
    auto mfmaPhase = [&]() {
#pragma unroll
        for (int kk = 0; kk < 2; ++kk) {
            const int clog = (kk << 2) + lg;
            bf16x8 bfr[4], afr[4];
#pragma unroll
            for (int ni = 0; ni < 4; ++ni) {
                int row = wc * 64 + ni * 16 + l15;
                bfr[ni] = *(const bf16x8*)&Bs[row * 64 + ((clog ^ (row & 7)) << 3)];
            }
            if constexpr (V == 1) {
#pragma unroll
                for (int mi = 0; mi < 4; ++mi) afr[mi] = Og[mi];
            } else {
#pragma unroll
                for (int mi = 0; mi < 4; ++mi) {
                    int row = wr * 64 + mi * 16 + l15;
                    afr[mi] = *(const bf16x8*)&As[row * 64 + ((clog ^ (row & 7)) << 3)];
                }
            }
            if constexpr (V == 2) {
                asm volatile("" :: "v"(afr[0]), "v"(afr[1]), "v"(afr[2]), "v"(afr[3]),
                                   "v"(bfr[0]), "v"(bfr[1]), "v"(bfr[2]), "v"(bfr[3]));
            } else {
                __builtin_amdgcn_s_setprio(1);
#pragma unroll
                for (int mi = 0; mi < 4; ++mi)
#pragma unroll
                    for (int ni = 0; ni < 4; ++ni)
                        acc[mi][ni] = __builtin_amdgcn_mfma_f32_16x16x32_bf16(
                            afr[mi], bfr[ni], acc[mi][ni], 0, 0, 0);
                __builtin_amdgcn_s_setprio(0);
            }
        }
    };

    loadA(0);
    if constexpr (V != 3) stageB(0);

#pragma unroll 1
    for (int tt = 0; tt < 80; ++tt) {
        const int knext = ((tt + 1) % 10) * 64;
        genA();
        if (tt < 79) loadA(knext);
        if (tt < 79) { WAIT_VM(8); } else { WAIT_VM(0); }
        WAIT_LGKM0();
        if constexpr (V != 4) BARRIER();
        mfmaPhase();
        if constexpr (V != 4) BARRIER();
        if (tt < 79 && V != 3) stageB(knext);
    }

    float bv[4];
#pragma unroll
    for (int ni = 0; ni < 4; ++ni) bv[ni] = b2[n0 + wc * 64 + ni * 16 + l15];
#pragma unroll
    for (int mi = 0; mi < 4; ++mi) {
#pragma unroll
        for (int ni = 0; ni < 4; ++ni) {
            int col = n0 + wc * 64 + ni * 16 + l15;
#pragma unroll
            for (int j = 0; j < 4; ++j) {
                int row = m0 + wr * 64 + mi * 16 + lg * 4 + j;
                out[(size_t)row * 1024 + col] = acc[mi][ni][j] + bv[ni];
            }
        }
    }
}

// ---------------------------------------------------------------------------
// Final correct kernel: R6-exact (best so far). Fully overwrites d_out.
// ---------------------------------------------------------------------------
__global__ __launch_bounds__(256, 3) void joint_main(
    const bf16* __restrict__ hf, const bf16* __restrict__ hgb,
    const bf16* __restrict__ W2T, const float* __restrict__ b2,
    float* __restrict__ out)
{
    __shared__ bf16 As[128 * 64];
    __shared__ bf16 Bs[128 * 64];
    const int tid = threadIdx.x;
    const int n0 = blockIdx.x * 128;
    const int m0 = blockIdx.y * 128;

    const int r  = tid >> 1;
    const int kh = (tid & 1) << 5;
    const int c0 = (tid & 1) << 2;
    int aoff[4];
#pragma unroll
    for (int c = 0; c < 4; ++c)
        aoff[c] = r * 64 + (((c0 + c) ^ (r & 7)) << 3);

    const int m  = m0 + r;
    const int bt = m / 65;
    const int uu = m - bt * 65;
    const int bb = bt >> 8;
    const bf16* hfp = hf  + (size_t)bt * 640 + kh;
    const bf16* hgp = hgb + (size_t)(bb * 65 + uu) * 640 + kh;

    const int wid = tid >> 6, lane = tid & 63;
    const int wr = wid >> 1, wc = wid & 1;
    const int lg = lane >> 4, l15 = lane & 15;

    f32x4 acc[4][4] = {};
    bf16x8 F[4], G[4];

    auto loadA = [&](int k0) {
#pragma unroll
        for (int i = 0; i < 4; ++i) {
            F[i] = *(const bf16x8*)(hfp + k0 + i * 8);
            G[i] = *(const bf16x8*)(hgp + k0 + i * 8);
        }
    };
    auto stageB = [&](int k0) {
        const char* w2b = (const char*)W2T + (size_t)k0 * 2;
#pragma unroll
        for (int call = 0; call < 4; ++call) {
            int chunk = call * 256 + tid;
            int brow = chunk >> 3, c = chunk & 7;
            const char* src = w2b + (size_t)(n0 + brow) * 1280
                                  + ((c ^ (brow & 7)) << 4);
            __builtin_amdgcn_global_load_lds(
                (const __attribute__((address_space(1))) uint32_t*)src,
                (__attribute__((address_space(3))) uint32_t*)&Bs[chunk << 3],
                16, 0, 0);
        }
    };
    auto genA = [&]() {
#pragma unroll
        for (int c = 0; c < 4; ++c) {
            bf16x8 O;
#pragma unroll
            for (int i = 0; i < 8; ++i) {
                float s = (float)F[c][i] + (float)G[c][i];
                O[i] = (bf16)fmaxf(s, 0.f);
            }
            *(bf16x8*)&As[aoff[c]] = O;
        }
    };
    auto mfmaPhase = [&]() {
#pragma unroll
        for (int kk = 0; kk < 2; ++kk) {
            const int clog = (kk << 2) + lg;
            bf16x8 bfr[4], afr[4];
#pragma unroll
            for (int ni = 0; ni < 4; ++ni) {
                int row = wc * 64 + ni * 16 + l15;
                bfr[ni] = *(const bf16x8*)&Bs[row * 64 + ((clog ^ (row & 7)) << 3)];
            }
#pragma unroll
            for (int mi = 0; mi < 4; ++mi) {
                int row = wr * 64 + mi * 16 + l15;
                afr[mi] = *(const bf16x8*)&As[row * 64 + ((clog ^ (row & 7)) << 3)];
            }
#pragma unroll
            for (int mi = 0; mi < 4; ++mi)
#pragma unroll
                for (int ni = 0; ni < 4; ++ni)
                    acc[mi][ni] = __builtin_amdgcn_mfma_f32_16x16x32_bf16(
                        afr[mi], bfr[ni], acc[mi][ni], 0, 0, 0);
        }
    };

    loadA(0);
    stageB(0);

#pragma unroll 1
    for (int t = 0; t < 10; ++t) {
        genA();
        if (t < 9) loadA((t + 1) * 64);
        if (t < 9) { WAIT_VM(8); } else { WAIT_VM(0); }
        WAIT_LGKM0();
        BARRIER();
        mfmaPhase();
        BARRIER();
        if (t < 9) stageB((t + 1) * 64);
    }

    float bv[4];
#pragma unroll
    for (int ni = 0; ni < 4; ++ni) bv[ni] = b2[n0 + wc * 64 + ni * 16 + l15];
#pragma unroll
    for (int mi = 0; mi < 4; ++mi) {
#pragma unroll
        for (int ni = 0; ni < 4; ++ni) {
            int col = n0 + wc * 64 + ni * 16 + l15;
#pragma unroll
            for (int j = 0; j < 4; ++j) {
                int row = m0 + wr * 64 + mi * 16 + lg * 4 + j;
                out[(size_t)row * 1024 + col] = acc[mi][ni][j] + bv[ni];
            }
        }
    }
}

// ---------------------------------------------------------------------------
extern "C" void kernel_launch(void* const* d_in, const int* in_sizes, int n_in,
                              void* d_out, int out_size, void* d_ws, size_t ws_size,
                              hipStream_t stream)
{
    const float* f  = (const float*)d_in[0];
    const float* g  = (const float*)d_in[1];
    const float* W1 = (const float*)d_in[2];
    const float* b1 = (const float*)d_in[3];
    const float* W2 = (const float*)d_in[4];
    const float* b2 = (const float*)d_in[5];
    float* out = (float*)d_out;

    bf16* hf  = (bf16*)d_ws;
    bf16* hgb = hf + 2048 * 640;
    bf16* W2T = hgb + 520 * 640;

    prep<<<1050, 256, 0, stream>>>(f, g, W1, b1, W2, hf, hgb, W2T);

    // ---- ablation probes (half grid, 80 K-iters each; output overwritten) ----
    joint_probe<0><<<dim3(8, 520), 256, 0, stream>>>(hf, hgb, W2T, b2, out);
    joint_probe<1><<<dim3(8, 520), 256, 0, stream>>>(hf, hgb, W2T, b2, out);
    joint_probe<2><<<dim3(8, 520), 256, 0, stream>>>(hf, hgb, W2T, b2, out);
    joint_probe<3><<<dim3(8, 520), 256, 0, stream>>>(hf, hgb, W2T, b2, out);
    joint_probe<4><<<dim3(8, 520), 256, 0, stream>>>(hf, hgb, W2T, b2, out);

    // ---- final correct kernel (R6-exact), overwrites all of d_out ----
    joint_main<<<dim3(8, 1040), 256, 0, stream>>>(hf, hgb, W2T, b2, out);
}

// Round 12
// 452.623 us; speedup vs baseline: 8.7269x; 8.7269x over previous
//
#include <hip/hip_runtime.h>
#include <cstdint>

typedef __bf16 bf16;
typedef __bf16 bf16x8 __attribute__((ext_vector_type(8)));
typedef float  f32x4  __attribute__((ext_vector_type(4)));

#define BARRIER()    asm volatile("s_barrier" ::: "memory")
#define WAIT_LGKM0() asm volatile("s_waitcnt lgkmcnt(0)" ::: "memory")
#define WAIT_VM(n)   asm volatile("s_waitcnt vmcnt(" #n ")" ::: "memory")

// ---------------------------------------------------------------------------
// Fused prep kernel: hf-GEMM (320 blocks) | hg-GEMM (90) | W2 transpose (640).
// ---------------------------------------------------------------------------
__device__ void gemm_small_body(
    const float* __restrict__ A, const float* __restrict__ Bm,
    const float* __restrict__ bias, bf16* __restrict__ Cout,
    int M, int N, int K, int bx, int by)
{
    __shared__ float As[64][20];
    __shared__ float Bs[16][68];
    const int tid = threadIdx.x;
    const int m0 = bx * 64, n0 = by * 64;
    const int tx = tid & 15, ty = tid >> 4;
    const int arow = tid >> 2, ak = (tid & 3) << 2;
    const int bk = tid >> 4, bc = (tid & 15) << 2;
    const bool avalid = (m0 + arow) < M;
    float acc[4][4] = {};

    for (int k0 = 0; k0 < K; k0 += 16) {
        float4 av = make_float4(0.f, 0.f, 0.f, 0.f);
        if (avalid) av = *(const float4*)&A[(size_t)(m0 + arow) * K + k0 + ak];
        float4 bv = *(const float4*)&Bm[(size_t)(k0 + bk) * N + n0 + bc];
        __syncthreads();
        *(float4*)&As[arow][ak] = av;
        *(float4*)&Bs[bk][bc] = bv;
        __syncthreads();
#pragma unroll
        for (int k = 0; k < 16; ++k) {
            float a[4], b[4];
#pragma unroll
            for (int i = 0; i < 4; ++i) a[i] = As[ty * 4 + i][k];
#pragma unroll
            for (int j = 0; j < 4; ++j) b[j] = Bs[k][tx * 4 + j];
#pragma unroll
            for (int i = 0; i < 4; ++i)
#pragma unroll
                for (int j = 0; j < 4; ++j) acc[i][j] += a[i] * b[j];
        }
    }
#pragma unroll
    for (int i = 0; i < 4; ++i) {
        int row = m0 + ty * 4 + i;
        if (row >= M) continue;
#pragma unroll
        for (int j = 0; j < 4; ++j) {
            int col = n0 + tx * 4 + j;
            float v = acc[i][j] + (bias ? bias[col] : 0.f);
            Cout[(size_t)row * N + col] = (bf16)v;
        }
    }
}

__device__ void w2t_body(const float* __restrict__ W2, bf16* __restrict__ W2T,
                         int bx, int by)
{
    __shared__ float t[32][33];
    const int tx = threadIdx.x & 31, ty = threadIdx.x >> 5;  // 32 x 8
    const int n0 = bx * 32, k0 = by * 32;
#pragma unroll
    for (int i = 0; i < 4; ++i)
        t[ty + i * 8][tx] = W2[(size_t)(k0 + ty + i * 8) * 1024 + n0 + tx];
    __syncthreads();
#pragma unroll
    for (int i = 0; i < 4; ++i)
        W2T[(size_t)(n0 + ty + i * 8) * 640 + k0 + tx] = (bf16)t[tx][ty + i * 8];
}

__global__ __launch_bounds__(256) void prep(
    const float* __restrict__ f, const float* __restrict__ g,
    const float* __restrict__ W1, const float* __restrict__ b1,
    const float* __restrict__ W2,
    bf16* __restrict__ hf, bf16* __restrict__ hgb, bf16* __restrict__ W2T)
{
    const int bid = blockIdx.x;
    if (bid < 320) {
        gemm_small_body(f, W1, nullptr, hf, 2048, 640, 1024, bid % 32, bid / 32);
    } else if (bid < 410) {
        int b = bid - 320;
        gemm_small_body(g, W1 + 1024 * 640, b1, hgb, 520, 640, 320, b % 9, b / 9);
    } else {
        int b = bid - 410;
        w2t_body(W2, W2T, b % 32, b / 32);
    }
}

// ---------------------------------------------------------------------------
// hgen: materialize h[m][k] = relu(hf[bt][k] + hgb[bb*65+uu][k]), bf16.
// 133120 x 640 = 170 MB. Write-bound (~30 us). Fully coalesced 16B chunks.
// Same rounding as the old fused genA -> identical numerics.
// ---------------------------------------------------------------------------
__global__ __launch_bounds__(256) void hgen(
    const bf16* __restrict__ hf, const bf16* __restrict__ hgb,
    bf16* __restrict__ h)
{
    const uint32_t base = blockIdx.x * 5120u;   // 5120 chunks per block
#pragma unroll 4
    for (int i = 0; i < 20; ++i) {
        uint32_t chunk = base + i * 256u + threadIdx.x;   // < 10,649,600
        uint32_t r = chunk / 80u;                         // row 0..133119
        uint32_t c = chunk - r * 80u;                     // 16B chunk in row
        uint32_t bt = r / 65u;
        uint32_t uu = r - bt * 65u;
        uint32_t bb = bt >> 8;
        bf16x8 F = *(const bf16x8*)(hf  + (size_t)bt * 640 + c * 8);
        bf16x8 G = *(const bf16x8*)(hgb + (size_t)(bb * 65 + uu) * 640 + c * 8);
        bf16x8 O;
#pragma unroll
        for (int j = 0; j < 8; ++j) {
            float s = (float)F[j] + (float)G[j];
            O[j] = (bf16)fmaxf(s, 0.f);
        }
        *(bf16x8*)(h + (size_t)r * 640 + c * 8) = O;
    }
}

// ---------------------------------------------------------------------------
// joint_dma: pure GEMM out = h @ W2T^T + b2. BM=BN=128 BK=64, 256 thr =
// 4 waves (2Mx2N), wave tile 64x64 (64 AGPR). LDS 64 KB: As[2]+Bs[2]
// double-buffered, both staged via global_load_lds (zero VALU data path),
// XOR-swizzled 16B chunks. T3-minimum 2-phase: stage(t+1)->back buffer,
// ds_read+MFMA(cur), vm0 (aged one full MFMA phase), ONE barrier per tile.
// XCD-swizzled grid: the 8 n0-siblings of each m0 run on one XCD -> h
// re-reads are L2-local.
// ---------------------------------------------------------------------------
__global__ __launch_bounds__(256, 2) void joint_dma(
    const bf16* __restrict__ h, const bf16* __restrict__ W2T,
    const float* __restrict__ b2, float* __restrict__ out)
{
    __shared__ bf16 As[2][128 * 64];     // 32 KB
    __shared__ bf16 Bs[2][128 * 64];     // 32 KB
    const int tid = threadIdx.x;

    // --- bijective XCD swizzle (nwg = 8320 = 8*1040) ---
    const int d   = blockIdx.x;
    const int xcd = d & 7;
    const int s   = d >> 3;              // 0..1039
    const int n0  = (s & 7) * 128;
    const int m0  = (((s >> 3) << 3) + xcd) * 128;   // (s/8)*8 + xcd in 0..1039

    // --- staging mapping: thread -> (row r0+32*call, chunk c) ---
    const int r0 = tid >> 3;             // 0..31
    const int c  = tid & 7;
    const int csw = (c ^ (r0 & 7)) << 4; // swizzled byte offset within row
    const char* asrc[4];
    const char* bsrc[4];
#pragma unroll
    for (int call = 0; call < 4; ++call) {
        asrc[call] = (const char*)h   + (size_t)(m0 + r0 + call * 32) * 1280 + csw;
        bsrc[call] = (const char*)W2T + (size_t)(n0 + r0 + call * 32) * 1280 + csw;
    }

    // --- wave mapping: 2 (M) x 2 (N), wave tile 64x64 ---
    const int wid = tid >> 6, lane = tid & 63;
    const int wr = wid >> 1, wc = wid & 1;
    const int lg = lane >> 4, l15 = lane & 15;

    f32x4 acc[4][4] = {};

    auto stage = [&](int buf, int k0) {  // 8 x global_load_lds(16B)
        const size_t kb = (size_t)k0 * 2;
#pragma unroll
        for (int call = 0; call < 4; ++call) {
            int chunk = call * 256 + tid;
            __builtin_amdgcn_global_load_lds(
                (const __attribute__((address_space(1))) uint32_t*)(asrc[call] + kb),
                (__attribute__((address_space(3))) uint32_t*)&As[buf][chunk << 3],
                16, 0, 0);
        }
#pragma unroll
        for (int call = 0; call < 4; ++call) {
            int chunk = call * 256 + tid;
            __builtin_amdgcn_global_load_lds(
                (const __attribute__((address_space(1))) uint32_t*)(bsrc[call] + kb),
                (__attribute__((address_space(3))) uint32_t*)&Bs[buf][chunk << 3],
                16, 0, 0);
        }
    };
    auto mfmaPhase = [&](int buf) {
#pragma unroll
        for (int kk = 0; kk < 2; ++kk) {
            const int clog = (kk << 2) + lg;
            bf16x8 bfr[4], afr[4];
#pragma unroll
            for (int ni = 0; ni < 4; ++ni) {
                int row = wc * 64 + ni * 16 + l15;
                bfr[ni] = *(const bf16x8*)&Bs[buf][row * 64 + ((clog ^ (row & 7)) << 3)];
            }
#pragma unroll
            for (int mi = 0; mi < 4; ++mi) {
                int row = wr * 64 + mi * 16 + l15;
                afr[mi] = *(const bf16x8*)&As[buf][row * 64 + ((clog ^ (row & 7)) << 3)];
            }
            __builtin_amdgcn_s_setprio(1);
#pragma unroll
            for (int mi = 0; mi < 4; ++mi)
#pragma unroll
                for (int ni = 0; ni < 4; ++ni)
                    acc[mi][ni] = __builtin_amdgcn_mfma_f32_16x16x32_bf16(
                        afr[mi], bfr[ni], acc[mi][ni], 0, 0, 0);
            __builtin_amdgcn_s_setprio(0);
        }
    };

    // ---- prologue ----
    stage(0, 0);
    WAIT_VM(0);
    BARRIER();

    // ---- main loop: 10 tiles, 1 barrier + 1 aged vm0 per tile ----
#pragma unroll 1
    for (int t = 0; t < 10; ++t) {
        const int cur = t & 1;
        if (t < 9) stage(cur ^ 1, (t + 1) * 64);  // DMA flight = MFMA phase
        mfmaPhase(cur);
        WAIT_VM(0);                               // stage(t+1) deposited
        BARRIER();                                // all reads(t) + DMA(t+1) done
    }

    // ---- epilogue: +b2, fp32 stores ----
    float bv[4];
#pragma unroll
    for (int ni = 0; ni < 4; ++ni) bv[ni] = b2[n0 + wc * 64 + ni * 16 + l15];
#pragma unroll
    for (int mi = 0; mi < 4; ++mi) {
#pragma unroll
        for (int ni = 0; ni < 4; ++ni) {
            int col = n0 + wc * 64 + ni * 16 + l15;
#pragma unroll
            for (int j = 0; j < 4; ++j) {
                int row = m0 + wr * 64 + mi * 16 + lg * 4 + j;
                out[(size_t)row * 1024 + col] = acc[mi][ni][j] + bv[ni];
            }
        }
    }
}

// ---------------------------------------------------------------------------
// Fallback (ws too small for h): R6-exact fused kernel, 3 blocks/CU.
// ---------------------------------------------------------------------------
__global__ __launch_bounds__(256, 3) void joint_main(
    const bf16* __restrict__ hf, const bf16* __restrict__ hgb,
    const bf16* __restrict__ W2T, const float* __restrict__ b2,
    float* __restrict__ out)
{
    __shared__ bf16 As[128 * 64];
    __shared__ bf16 Bs[128 * 64];
    const int tid = threadIdx.x;
    const int n0 = blockIdx.x * 128;
    const int m0 = blockIdx.y * 128;

    const int r  = tid >> 1;
    const int kh = (tid & 1) << 5;
    const int c0 = (tid & 1) << 2;
    int aoff[4];
#pragma unroll
    for (int c = 0; c < 4; ++c)
        aoff[c] = r * 64 + (((c0 + c) ^ (r & 7)) << 3);

    const int m  = m0 + r;
    const int bt = m / 65;
    const int uu = m - bt * 65;
    const int bb = bt >> 8;
    const bf16* hfp = hf  + (size_t)bt * 640 + kh;
    const bf16* hgp = hgb + (size_t)(bb * 65 + uu) * 640 + kh;

    const int wid = tid >> 6, lane = tid & 63;
    const int wr = wid >> 1, wc = wid & 1;
    const int lg = lane >> 4, l15 = lane & 15;

    f32x4 acc[4][4] = {};
    bf16x8 F[4], G[4];

    auto loadA = [&](int k0) {
#pragma unroll
        for (int i = 0; i < 4; ++i) {
            F[i] = *(const bf16x8*)(hfp + k0 + i * 8);
            G[i] = *(const bf16x8*)(hgp + k0 + i * 8);
        }
    };
    auto stageB = [&](int k0) {
        const char* w2b = (const char*)W2T + (size_t)k0 * 2;
#pragma unroll
        for (int call = 0; call < 4; ++call) {
            int chunk = call * 256 + tid;
            int brow = chunk >> 3, c = chunk & 7;
            const char* src = w2b + (size_t)(n0 + brow) * 1280
                                  + ((c ^ (brow & 7)) << 4);
            __builtin_amdgcn_global_load_lds(
                (const __attribute__((address_space(1))) uint32_t*)src,
                (__attribute__((address_space(3))) uint32_t*)&Bs[chunk << 3],
                16, 0, 0);
        }
    };
    auto genA = [&]() {
#pragma unroll
        for (int c = 0; c < 4; ++c) {
            bf16x8 O;
#pragma unroll
            for (int i = 0; i < 8; ++i) {
                float s = (float)F[c][i] + (float)G[c][i];
                O[i] = (bf16)fmaxf(s, 0.f);
            }
            *(bf16x8*)&As[aoff[c]] = O;
        }
    };
    auto mfmaPhase = [&]() {
#pragma unroll
        for (int kk = 0; kk < 2; ++kk) {
            const int clog = (kk << 2) + lg;
            bf16x8 bfr[4], afr[4];
#pragma unroll
            for (int ni = 0; ni < 4; ++ni) {
                int row = wc * 64 + ni * 16 + l15;
                bfr[ni] = *(const bf16x8*)&Bs[row * 64 + ((clog ^ (row & 7)) << 3)];
            }
#pragma unroll
            for (int mi = 0; mi < 4; ++mi) {
                int row = wr * 64 + mi * 16 + l15;
                afr[mi] = *(const bf16x8*)&As[row * 64 + ((clog ^ (row & 7)) << 3)];
            }
#pragma unroll
            for (int mi = 0; mi < 4; ++mi)
#pragma unroll
                for (int ni = 0; ni < 4; ++ni)
                    acc[mi][ni] = __builtin_amdgcn_mfma_f32_16x16x32_bf16(
                        afr[mi], bfr[ni], acc[mi][ni], 0, 0, 0);
        }
    };

    loadA(0);
    stageB(0);

#pragma unroll 1
    for (int t = 0; t < 10; ++t) {
        genA();
        if (t < 9) loadA((t + 1) * 64);
        if (t < 9) { WAIT_VM(8); } else { WAIT_VM(0); }
        WAIT_LGKM0();
        BARRIER();
        mfmaPhase();
        BARRIER();
        if (t < 9) stageB((t + 1) * 64);
    }

    float bv[4];
#pragma unroll
    for (int ni = 0; ni < 4; ++ni) bv[ni] = b2[n0 + wc * 64 + ni * 16 + l15];
#pragma unroll
    for (int mi = 0; mi < 4; ++mi) {
#pragma unroll
        for (int ni = 0; ni < 4; ++ni) {
            int col = n0 + wc * 64 + ni * 16 + l15;
#pragma unroll
            for (int j = 0; j < 4; ++j) {
                int row = m0 + wr * 64 + mi * 16 + lg * 4 + j;
                out[(size_t)row * 1024 + col] = acc[mi][ni][j] + bv[ni];
            }
        }
    }
}

// ---------------------------------------------------------------------------
extern "C" void kernel_launch(void* const* d_in, const int* in_sizes, int n_in,
                              void* d_out, int out_size, void* d_ws, size_t ws_size,
                              hipStream_t stream)
{
    const float* f  = (const float*)d_in[0];
    const float* g  = (const float*)d_in[1];
    const float* W1 = (const float*)d_in[2];
    const float* b1 = (const float*)d_in[3];
    const float* W2 = (const float*)d_in[4];
    const float* b2 = (const float*)d_in[5];
    float* out = (float*)d_out;

    bf16* hf  = (bf16*)d_ws;                     // 2048*640
    bf16* hgb = hf + 2048 * 640;                 // 520*640
    bf16* W2T = hgb + 520 * 640;                 // 1024*640
    bf16* h   = W2T + 1024 * 640;                // 133120*640 (170 MB)

    const size_t need = ((size_t)(2048 + 520 + 1024) + 133120) * 640 * 2;

    prep<<<1050, 256, 0, stream>>>(f, g, W1, b1, W2, hf, hgb, W2T);

    if (ws_size >= need) {
        hgen<<<2080, 256, 0, stream>>>(hf, hgb, h);
        joint_dma<<<8320, 256, 0, stream>>>(h, W2T, b2, out);
    } else {
        joint_main<<<dim3(8, 1040), 256, 0, stream>>>(hf, hgb, W2T, b2, out);
    }
}

// Round 13
// 451.366 us; speedup vs baseline: 8.7512x; 1.0028x over previous
//
#include <hip/hip_runtime.h>
#include <cstdint>

typedef __bf16 bf16;
typedef __bf16 bf16x8 __attribute__((ext_vector_type(8)));
typedef float  f32x4  __attribute__((ext_vector_type(4)));

// ---------------------------------------------------------------------------
// prep: hf-GEMM (blocks 0..319) | hg-GEMM (320..409) | W2 fragment-pack
// (410..729). w2f chunk layout: [nb 8][p 20][wc 2][ni 4][lane 64] x 16B,
// holding W2bf16[n = nb*128+wc*64+ni*16+l15][k = (p>>1)*64+(p&1)*32+lg*8 ..+7]
// with lane = lg*16 + l15  (exact mfma_16x16x32 B-fragment order).
// ---------------------------------------------------------------------------
__device__ void gemm_small_body(
    const float* __restrict__ A, const float* __restrict__ Bm,
    const float* __restrict__ bias, bf16* __restrict__ Cout,
    int M, int N, int K, int bx, int by)
{
    __shared__ float As[64][20];
    __shared__ float Bs[16][68];
    const int tid = threadIdx.x;
    const int m0 = bx * 64, n0 = by * 64;
    const int tx = tid & 15, ty = tid >> 4;
    const int arow = tid >> 2, ak = (tid & 3) << 2;
    const int bk = tid >> 4, bc = (tid & 15) << 2;
    const bool avalid = (m0 + arow) < M;
    float acc[4][4] = {};

    for (int k0 = 0; k0 < K; k0 += 16) {
        float4 av = make_float4(0.f, 0.f, 0.f, 0.f);
        if (avalid) av = *(const float4*)&A[(size_t)(m0 + arow) * K + k0 + ak];
        float4 bv = *(const float4*)&Bm[(size_t)(k0 + bk) * N + n0 + bc];
        __syncthreads();
        *(float4*)&As[arow][ak] = av;
        *(float4*)&Bs[bk][bc] = bv;
        __syncthreads();
#pragma unroll
        for (int k = 0; k < 16; ++k) {
            float a[4], b[4];
#pragma unroll
            for (int i = 0; i < 4; ++i) a[i] = As[ty * 4 + i][k];
#pragma unroll
            for (int j = 0; j < 4; ++j) b[j] = Bs[k][tx * 4 + j];
#pragma unroll
            for (int i = 0; i < 4; ++i)
#pragma unroll
                for (int j = 0; j < 4; ++j) acc[i][j] += a[i] * b[j];
        }
    }
#pragma unroll
    for (int i = 0; i < 4; ++i) {
        int row = m0 + ty * 4 + i;
        if (row >= M) continue;
#pragma unroll
        for (int j = 0; j < 4; ++j) {
            int col = n0 + tx * 4 + j;
            float v = acc[i][j] + (bias ? bias[col] : 0.f);
            Cout[(size_t)row * N + col] = (bf16)v;
        }
    }
}

__global__ __launch_bounds__(256) void prep(
    const float* __restrict__ f, const float* __restrict__ g,
    const float* __restrict__ W1, const float* __restrict__ b1,
    const float* __restrict__ W2,
    bf16* __restrict__ hf, bf16* __restrict__ hgb, bf16* __restrict__ w2f)
{
    const int bid = blockIdx.x;
    if (bid < 320) {
        gemm_small_body(f, W1, nullptr, hf, 2048, 640, 1024, bid % 32, bid / 32);
    } else if (bid < 410) {
        int b = bid - 320;
        gemm_small_body(g, W1 + 1024 * 640, b1, hgb, 520, 640, 320, b % 9, b / 9);
    } else {
        // ---- W2 fragment pack: 81920 chunks of 16B ----
        int c = (bid - 410) * 256 + threadIdx.x;       // 0..81919
        int lane = c & 63;
        int ni   = (c >> 6) & 3;
        int q    = c >> 8;                              // 0..319
        int wc   = q & 1;
        int qq   = q >> 1;                              // 0..159
        int p    = qq % 20;
        int nb   = qq / 20;
        int n = nb * 128 + wc * 64 + ni * 16 + (lane & 15);
        int k = (p >> 1) * 64 + (p & 1) * 32 + (lane >> 4) * 8;
        bf16x8 O;
#pragma unroll
        for (int j = 0; j < 8; ++j)
            O[j] = (bf16)W2[(size_t)(k + j) * 1024 + n];
        ((bf16x8*)w2f)[c] = O;
    }
}

// ---------------------------------------------------------------------------
// hgen: materialize h = relu(hf + hgb) DIRECTLY in A-fragment order:
// hp chunk layout per mb: [q=2p+wr (40)][mi 4][lane 64] x 16B, holding
// h[row = mb*128+wr*64+mi*16+l15][k = (p>>1)*64+(p&1)*32+lg*8 ..+7].
// Writes coalesced (consecutive tid -> consecutive 16B); reads are 64B-chunk
// gathers from L2-resident hf/hgb. 170 MB write-bound (~30 us).
// ---------------------------------------------------------------------------
__global__ __launch_bounds__(256) void hgen(
    const bf16* __restrict__ hf, const bf16* __restrict__ hgb,
    bf16* __restrict__ hp)
{
    const int mb = blockIdx.x;                 // 0..1039
    bf16x8* outv = (bf16x8*)hp + (size_t)mb * 10240;
#pragma unroll 4
    for (int i = 0; i < 40; ++i) {
        int c = i * 256 + threadIdx.x;         // 0..10239
        int lane = c & 63;
        int mi   = (c >> 6) & 3;
        int q    = c >> 8;                      // 0..39
        int wr   = q & 1;
        int p    = q >> 1;                      // 0..19
        int row = mb * 128 + wr * 64 + mi * 16 + (lane & 15);
        int k   = (p >> 1) * 64 + (p & 1) * 32 + (lane >> 4) * 8;
        int bt = row / 65;
        int uu = row - bt * 65;
        int bb = bt >> 8;
        bf16x8 F = *(const bf16x8*)(hf  + (size_t)bt * 640 + k);
        bf16x8 G = *(const bf16x8*)(hgb + (size_t)(bb * 65 + uu) * 640 + k);
        bf16x8 O;
#pragma unroll
        for (int j = 0; j < 8; ++j) {
            float s = (float)F[j] + (float)G[j];
            O[j] = (bf16)fmaxf(s, 0.f);
        }
        outv[c] = O;
    }
}

// ---------------------------------------------------------------------------
// joint_frag: LDS-FREE, BARRIER-FREE fragment GEMM.
// BM=BN=128, 256 thr = 4 waves (2Mx2N), wave tile 64x64 (64 AGPR acc).
// Per kk-phase: 8 coalesced 16B/lane global loads (L2-hit, fragment-direct)
// + 16 MFMA. Register double-buffer, 1 phase lookahead; latency hidden by
// 12 waves/CU (3 blocks/CU). XCD swizzle: mb's 8 nb-siblings on one XCD.
// ---------------------------------------------------------------------------
__global__ __launch_bounds__(256, 3) void joint_frag(
    const bf16* __restrict__ hp, const bf16* __restrict__ w2f,
    const float* __restrict__ b2, float* __restrict__ out)
{
    const int tid = threadIdx.x;
    const int d   = blockIdx.x;                // 0..8319
    const int xcd = d & 7;
    const int s   = d >> 3;                    // 0..1039
    const int nb  = s & 7;
    const int mb  = ((s >> 3) << 3) + xcd;     // 0..1039

    const int wid = tid >> 6, lane = tid & 63;
    const int wr = wid >> 1, wc = wid & 1;
    const int lg = lane >> 4, l15 = lane & 15;

    const bf16x8* av = (const bf16x8*)hp;
    const bf16x8* bv = (const bf16x8*)w2f;
    // chunk index = (mb*40 + 2p + wr)*256 + mi*64 + lane
    const size_t abase = ((size_t)mb * 40 + wr) * 256 + lane;
    const size_t bbase = ((size_t)nb * 40 + wc) * 256 + lane;

    f32x4 acc[4][4] = {};
    bf16x8 A0[4], B0[4], A1[4], B1[4];

#define LOADP(A, B, P)                                                        \
    { const size_t ao = abase + (size_t)(P) * 512;                            \
      const size_t bo = bbase + (size_t)(P) * 512;                            \
      _Pragma("unroll")                                                       \
      for (int mi = 0; mi < 4; ++mi) A[mi] = av[ao + mi * 64];                \
      _Pragma("unroll")                                                       \
      for (int ni = 0; ni < 4; ++ni) B[ni] = bv[bo + ni * 64]; }

#define MFMA16(A, B)                                                          \
    { __builtin_amdgcn_s_setprio(1);                                          \
      _Pragma("unroll")                                                       \
      for (int mi = 0; mi < 4; ++mi)                                          \
          _Pragma("unroll")                                                   \
          for (int ni = 0; ni < 4; ++ni)                                      \
              acc[mi][ni] = __builtin_amdgcn_mfma_f32_16x16x32_bf16(          \
                  A[mi], B[ni], acc[mi][ni], 0, 0, 0);                        \
      __builtin_amdgcn_s_setprio(0); }

    LOADP(A0, B0, 0);
#pragma unroll 1
    for (int p = 0; p < 20; p += 2) {
        LOADP(A1, B1, p + 1);                  // prefetch odd phase
        MFMA16(A0, B0);                        // compiler waits A0/B0 only
        if (p + 2 < 20) LOADP(A0, B0, p + 2);  // prefetch next even phase
        MFMA16(A1, B1);
    }
#undef LOADP
#undef MFMA16

    // ---- epilogue: +b2, fp32 stores ----
    const int m0 = mb * 128, n0 = nb * 128;
    float bvv[4];
#pragma unroll
    for (int ni = 0; ni < 4; ++ni) bvv[ni] = b2[n0 + wc * 64 + ni * 16 + l15];
#pragma unroll
    for (int mi = 0; mi < 4; ++mi) {
#pragma unroll
        for (int ni = 0; ni < 4; ++ni) {
            int col = n0 + wc * 64 + ni * 16 + l15;
#pragma unroll
            for (int j = 0; j < 4; ++j) {
                int row = m0 + wr * 64 + mi * 16 + lg * 4 + j;
                out[(size_t)row * 1024 + col] = acc[mi][ni][j] + bvv[ni];
            }
        }
    }
}

// ---------------------------------------------------------------------------
extern "C" void kernel_launch(void* const* d_in, const int* in_sizes, int n_in,
                              void* d_out, int out_size, void* d_ws, size_t ws_size,
                              hipStream_t stream)
{
    const float* f  = (const float*)d_in[0];   // (8,256,1024)
    const float* g  = (const float*)d_in[1];   // (8,65,320)
    const float* W1 = (const float*)d_in[2];   // (1344,640)
    const float* b1 = (const float*)d_in[3];   // (640)
    const float* W2 = (const float*)d_in[4];   // (640,1024)
    const float* b2 = (const float*)d_in[5];   // (1024)
    float* out = (float*)d_out;                // (8,256,65,1024)

    bf16* hf  = (bf16*)d_ws;                   // 2048*640        = 1,310,720
    bf16* hgb = hf  + 2048 * 640;              // 520*640         =   332,800
    bf16* w2f = hgb + 520 * 640;               // 81920*8         =   655,360
    bf16* hp  = w2f + 81920 * 8;               // 1040*10240*8    = 85,196,800

    prep<<<730, 256, 0, stream>>>(f, g, W1, b1, W2, hf, hgb, w2f);
    hgen<<<1040, 256, 0, stream>>>(hf, hgb, hp);
    joint_frag<<<8320, 256, 0, stream>>>(hp, w2f, b2, out);
}

// Round 14
// 392.279 us; speedup vs baseline: 10.0693x; 1.1506x over previous
//
#include <hip/hip_runtime.h>
#include <cstdint>

typedef __bf16 bf16;
typedef __bf16 bf16x8 __attribute__((ext_vector_type(8)));
typedef float  f32x4  __attribute__((ext_vector_type(4)));

#define BARRIER()    asm volatile("s_barrier" ::: "memory")
#define WAIT_LGKM0() asm volatile("s_waitcnt lgkmcnt(0)" ::: "memory")
#define WAIT_VM(n)   asm volatile("s_waitcnt vmcnt(" #n ")" ::: "memory")

// ---------------------------------------------------------------------------
// Fused prep kernel: hf-GEMM (320 blocks) | hg-GEMM (90) | W2 transpose (640).
// ---------------------------------------------------------------------------
__device__ void gemm_small_body(
    const float* __restrict__ A, const float* __restrict__ Bm,
    const float* __restrict__ bias, bf16* __restrict__ Cout,
    int M, int N, int K, int bx, int by)
{
    __shared__ float As[64][20];
    __shared__ float Bs[16][68];
    const int tid = threadIdx.x;
    const int m0 = bx * 64, n0 = by * 64;
    const int tx = tid & 15, ty = tid >> 4;
    const int arow = tid >> 2, ak = (tid & 3) << 2;
    const int bk = tid >> 4, bc = (tid & 15) << 2;
    const bool avalid = (m0 + arow) < M;
    float acc[4][4] = {};

    for (int k0 = 0; k0 < K; k0 += 16) {
        float4 av = make_float4(0.f, 0.f, 0.f, 0.f);
        if (avalid) av = *(const float4*)&A[(size_t)(m0 + arow) * K + k0 + ak];
        float4 bv = *(const float4*)&Bm[(size_t)(k0 + bk) * N + n0 + bc];
        __syncthreads();
        *(float4*)&As[arow][ak] = av;
        *(float4*)&Bs[bk][bc] = bv;
        __syncthreads();
#pragma unroll
        for (int k = 0; k < 16; ++k) {
            float a[4], b[4];
#pragma unroll
            for (int i = 0; i < 4; ++i) a[i] = As[ty * 4 + i][k];
#pragma unroll
            for (int j = 0; j < 4; ++j) b[j] = Bs[k][tx * 4 + j];
#pragma unroll
            for (int i = 0; i < 4; ++i)
#pragma unroll
                for (int j = 0; j < 4; ++j) acc[i][j] += a[i] * b[j];
        }
    }
#pragma unroll
    for (int i = 0; i < 4; ++i) {
        int row = m0 + ty * 4 + i;
        if (row >= M) continue;
#pragma unroll
        for (int j = 0; j < 4; ++j) {
            int col = n0 + tx * 4 + j;
            float v = acc[i][j] + (bias ? bias[col] : 0.f);
            Cout[(size_t)row * N + col] = (bf16)v;
        }
    }
}

__device__ void w2t_body(const float* __restrict__ W2, bf16* __restrict__ W2T,
                         int bx, int by)
{
    __shared__ float t[32][33];
    const int tx = threadIdx.x & 31, ty = threadIdx.x >> 5;  // 32 x 8
    const int n0 = bx * 32, k0 = by * 32;
#pragma unroll
    for (int i = 0; i < 4; ++i)
        t[ty + i * 8][tx] = W2[(size_t)(k0 + ty + i * 8) * 1024 + n0 + tx];
    __syncthreads();
#pragma unroll
    for (int i = 0; i < 4; ++i)
        W2T[(size_t)(n0 + ty + i * 8) * 640 + k0 + tx] = (bf16)t[tx][ty + i * 8];
}

__global__ __launch_bounds__(256) void prep(
    const float* __restrict__ f, const float* __restrict__ g,
    const float* __restrict__ W1, const float* __restrict__ b1,
    const float* __restrict__ W2,
    bf16* __restrict__ hf, bf16* __restrict__ hgb, bf16* __restrict__ W2T)
{
    const int bid = blockIdx.x;
    if (bid < 320) {
        gemm_small_body(f, W1, nullptr, hf, 2048, 640, 1024, bid % 32, bid / 32);
    } else if (bid < 410) {
        int b = bid - 320;
        gemm_small_body(g, W1 + 1024 * 640, b1, hgb, 520, 640, 320, b % 9, b / 9);
    } else {
        int b = bid - 410;
        w2t_body(W2, W2T, b % 32, b / 32);
    }
}

// ---------------------------------------------------------------------------
// joint_main: R6-exact fused K-loop (best known: 3 blocks/CU, 2 barriers/tile,
// counted vmcnt) + NEW LDS-bounce epilogue:
//   4 rounds of 32 rows; scatter acc+bias into padded ebuf[32][132];
//   barrier; read back coalesced; store float4/lane -> 1 KB contiguous
//   per instruction (full-line writes), vs old 4B/lane scattered stores.
// This targets the HBM-write roofline (write BW was pinned at ~1.9 TB/s
// across ALL prior structures; problem floor is write-bound at ~87 us).
// ---------------------------------------------------------------------------
__global__ __launch_bounds__(256, 3) void joint_main(
    const bf16* __restrict__ hf, const bf16* __restrict__ hgb,
    const bf16* __restrict__ W2T, const float* __restrict__ b2,
    float* __restrict__ out)
{
    __shared__ bf16 As[128 * 64];        // 16 KB
    __shared__ bf16 Bs[128 * 64];        // 16 KB
    __shared__ float ebuf[32 * 132];     // 16.9 KB epilogue bounce
    const int tid = threadIdx.x;
    const int n0 = blockIdx.x * 128;
    const int m0 = blockIdx.y * 128;

    const int r  = tid >> 1;
    const int kh = (tid & 1) << 5;
    const int c0 = (tid & 1) << 2;
    int aoff[4];
#pragma unroll
    for (int c = 0; c < 4; ++c)
        aoff[c] = r * 64 + (((c0 + c) ^ (r & 7)) << 3);

    const int m  = m0 + r;
    const int bt = m / 65;
    const int uu = m - bt * 65;
    const int bb = bt >> 8;
    const bf16* hfp = hf  + (size_t)bt * 640 + kh;
    const bf16* hgp = hgb + (size_t)(bb * 65 + uu) * 640 + kh;

    const int wid = tid >> 6, lane = tid & 63;
    const int wr = wid >> 1, wc = wid & 1;
    const int lg = lane >> 4, l15 = lane & 15;

    f32x4 acc[4][4] = {};
    bf16x8 F[4], G[4];

    auto loadA = [&](int k0) {
#pragma unroll
        for (int i = 0; i < 4; ++i) {
            F[i] = *(const bf16x8*)(hfp + k0 + i * 8);
            G[i] = *(const bf16x8*)(hgp + k0 + i * 8);
        }
    };
    auto stageB = [&](int k0) {
        const char* w2b = (const char*)W2T + (size_t)k0 * 2;
#pragma unroll
        for (int call = 0; call < 4; ++call) {
            int chunk = call * 256 + tid;
            int brow = chunk >> 3, c = chunk & 7;
            const char* src = w2b + (size_t)(n0 + brow) * 1280
                                  + ((c ^ (brow & 7)) << 4);
            __builtin_amdgcn_global_load_lds(
                (const __attribute__((address_space(1))) uint32_t*)src,
                (__attribute__((address_space(3))) uint32_t*)&Bs[chunk << 3],
                16, 0, 0);
        }
    };
    auto genA = [&]() {
#pragma unroll
        for (int c = 0; c < 4; ++c) {
            bf16x8 O;
#pragma unroll
            for (int i = 0; i < 8; ++i) {
                float s = (float)F[c][i] + (float)G[c][i];
                O[i] = (bf16)fmaxf(s, 0.f);
            }
            *(bf16x8*)&As[aoff[c]] = O;
        }
    };
    auto mfmaPhase = [&]() {
#pragma unroll
        for (int kk = 0; kk < 2; ++kk) {
            const int clog = (kk << 2) + lg;
            bf16x8 bfr[4], afr[4];
#pragma unroll
            for (int ni = 0; ni < 4; ++ni) {
                int row = wc * 64 + ni * 16 + l15;
                bfr[ni] = *(const bf16x8*)&Bs[row * 64 + ((clog ^ (row & 7)) << 3)];
            }
#pragma unroll
            for (int mi = 0; mi < 4; ++mi) {
                int row = wr * 64 + mi * 16 + l15;
                afr[mi] = *(const bf16x8*)&As[row * 64 + ((clog ^ (row & 7)) << 3)];
            }
#pragma unroll
            for (int mi = 0; mi < 4; ++mi)
#pragma unroll
                for (int ni = 0; ni < 4; ++ni)
                    acc[mi][ni] = __builtin_amdgcn_mfma_f32_16x16x32_bf16(
                        afr[mi], bfr[ni], acc[mi][ni], 0, 0, 0);
        }
    };

    loadA(0);
    stageB(0);

#pragma unroll 1
    for (int t = 0; t < 10; ++t) {
        genA();
        if (t < 9) loadA((t + 1) * 64);
        if (t < 9) { WAIT_VM(8); } else { WAIT_VM(0); }
        WAIT_LGKM0();
        BARRIER();
        mfmaPhase();
        BARRIER();
        if (t < 9) stageB((t + 1) * 64);
    }

    // ---- LDS-bounce epilogue: 4 rounds x 32 rows, float4 full-line stores --
    float bvv[4];
#pragma unroll
    for (int ni = 0; ni < 4; ++ni) bvv[ni] = b2[n0 + wc * 64 + ni * 16 + l15];

    const int row8 = tid >> 3;          // 0..31  (gather row in round)
    const int c8   = (tid & 7) << 4;    // gather col start: 0,16,..,112
    const int wrr  = row8 >> 4;         // 0..1
    const int rr   = row8 & 15;

#pragma unroll
    for (int mi = 0; mi < 4; ++mi) {
        BARRIER();                       // prior round's reads complete
        // scatter acc+bias -> ebuf (rows: wr*16+lg*4+j, cols: wc*64+ni*16+l15)
#pragma unroll
        for (int ni = 0; ni < 4; ++ni)
#pragma unroll
            for (int j = 0; j < 4; ++j)
                ebuf[(wr * 16 + lg * 4 + j) * 132 + wc * 64 + ni * 16 + l15]
                    = acc[mi][ni][j] + bvv[ni];
        WAIT_LGKM0();
        BARRIER();
        // gather + wide store: 8 threads/row, 4 x float4 each -> 1 KB/inst
        const int grow = m0 + wrr * 64 + mi * 16 + rr;
        float4* dst = (float4*)&out[(size_t)grow * 1024 + n0 + c8];
#pragma unroll
        for (int c = 0; c < 4; ++c) {
            float4 v = *(float4*)&ebuf[row8 * 132 + c8 + c * 4];
            dst[c] = v;
        }
    }
}

// ---------------------------------------------------------------------------
extern "C" void kernel_launch(void* const* d_in, const int* in_sizes, int n_in,
                              void* d_out, int out_size, void* d_ws, size_t ws_size,
                              hipStream_t stream)
{
    const float* f  = (const float*)d_in[0];
    const float* g  = (const float*)d_in[1];
    const float* W1 = (const float*)d_in[2];
    const float* b1 = (const float*)d_in[3];
    const float* W2 = (const float*)d_in[4];
    const float* b2 = (const float*)d_in[5];
    float* out = (float*)d_out;

    bf16* hf  = (bf16*)d_ws;
    bf16* hgb = hf + 2048 * 640;
    bf16* W2T = hgb + 520 * 640;

    prep<<<1050, 256, 0, stream>>>(f, g, W1, b1, W2, hf, hgb, W2T);
    joint_main<<<dim3(8, 1040), 256, 0, stream>>>(hf, hgb, W2T, b2, out);
}